// Round 6
// baseline (680.336 us; speedup 1.0000x reference)
//
#include <hip/hip_runtime.h>

#define NN 50000
#define NN64 50048
#define NE 600000
#define CC 128

typedef float f32x4 __attribute__((ext_vector_type(4)));
typedef float f32x2 __attribute__((ext_vector_type(2)));
typedef short bf16x8 __attribute__((ext_vector_type(8)));
typedef unsigned short u16x4 __attribute__((ext_vector_type(4)));
typedef unsigned short u16x8 __attribute__((ext_vector_type(8)));

__device__ __forceinline__ unsigned short f2b(float f) {
  union { float f; unsigned int u; } c; c.f = f;
  unsigned int r = c.u + 0x7FFFu + ((c.u >> 16) & 1u);
  return (unsigned short)(r >> 16);
}
__device__ __forceinline__ float blo(unsigned int u) {
  union { unsigned int x; float f; } c; c.x = u << 16; return c.f;
}
__device__ __forceinline__ float bhi(unsigned int u) {
  union { unsigned int x; float f; } c; c.x = u & 0xFFFF0000u; return c.f;
}
// async global->LDS 16B DMA (wave-uniform LDS base + lane*16 semantics; layouts kept linear)
__device__ __forceinline__ void gload16(const unsigned short* g, unsigned short* l) {
  __builtin_amdgcn_global_load_lds((const __attribute__((address_space(1))) void*)g,
                                   (__attribute__((address_space(3))) void*)l, 16, 0, 0);
}

union F4 { f32x4 v; struct { f32x2 lo, hi; } s; };

// ---------------- weight prep: bf16, transposed, XOR-swizzled LDS image ----------------
__global__ __launch_bounds__(256) void k_prep(const float* __restrict__ wih,
                                              const float* __restrict__ whh,
                                              const float* __restrict__ convW,
                                              unsigned short* __restrict__ wpack,
                                              unsigned short* __restrict__ cpack) {
  int i = blockIdx.x * 256 + threadIdx.x;
  if (i < 98304) {
    int k = i & 127, j = (i >> 7) & 127, half = (i >> 14) & 1, chunk = i >> 15;
    const float* srcm = half ? whh : wih;
    float v = srcm[(long)(chunk * 128 + j) * CC + k];
    wpack[(long)(((chunk * 2 + half) * 128 + j) << 7) + (k ^ ((j & 7) << 3))] = f2b(v);
  } else if (i < 131072) {
    int i2 = i - 98304;
    int k = i2 & 127, j = (i2 >> 7) & 127, layer = i2 >> 14;
    float v = convW[(long)(layer * 128 + k) * CC + j];
    cpack[(long)((layer * 128 + j) << 7) + (k ^ ((j & 7) << 3))] = f2b(v);
  }
}

// ---------------- BatchNorm ----------------
__global__ __launch_bounds__(128) void k_bnstats(const float* __restrict__ x,
                                                 float* __restrict__ stats) {
  int c = threadIdx.x;
  float s = 0.f, s2 = 0.f;
  for (int r = blockIdx.x; r < NN; r += gridDim.x) {
    float v = x[(long)r * CC + c];
    s += v; s2 += v * v;
  }
  atomicAdd(&stats[c], s);
  atomicAdd(&stats[CC + c], s2);
}

__global__ __launch_bounds__(128) void k_bnfinal(float* __restrict__ stats,
                                                 const float* __restrict__ gamma,
                                                 const float* __restrict__ beta) {
  int c = threadIdx.x;
  float mean = stats[c] * (1.f / NN);
  float var = stats[CC + c] * (1.f / NN) - mean * mean;
  var = fmaxf(var, 0.f);
  float sc = gamma[c] * rsqrtf(var + 1e-5f);
  stats[2 * CC + c] = sc;
  stats[3 * CC + c] = beta[c] - mean * sc;
}

// writes xh (f32) + xh_b (bf16, row-swizzled, for MFMA DMA staging)
__global__ __launch_bounds__(256) void k_norm(const float* __restrict__ x,
                                              const float* __restrict__ stats,
                                              float* __restrict__ xh,
                                              unsigned short* __restrict__ xhb) {
  const int total4 = NN * CC / 4;
  for (int i = blockIdx.x * 256 + threadIdx.x; i < total4; i += gridDim.x * 256) {
    f32x4 v = ((const f32x4*)x)[i];
    int c4 = (i & 31) * 4;
    int r = i >> 5;
    f32x4 sc = *(const f32x4*)&stats[2 * CC + c4];
    f32x4 sh = *(const f32x4*)&stats[3 * CC + c4];
    v = v * sc + sh;
    ((f32x4*)xh)[i] = v;
    u16x4 b; b.x = f2b(v[0]); b.y = f2b(v[1]); b.z = f2b(v[2]); b.w = f2b(v[3]);
    *(u16x4*)&xhb[(long)r * CC + (c4 ^ ((r & 7) << 3))] = b;
  }
}

// ---------------- CSR build ----------------
__global__ __launch_bounds__(256) void k_cnt(const int* __restrict__ dst, int* __restrict__ cnt) {
  for (int e = blockIdx.x * 256 + threadIdx.x; e < NE; e += gridDim.x * 256)
    atomicAdd(&cnt[dst[e]], 1);
}

__global__ __launch_bounds__(1024) void k_scan(const int* __restrict__ cnt, int* __restrict__ rowp) {
  __shared__ int part[1024];
  int t = threadIdx.x;
  const int CH = (NN + 1023) / 1024;  // 49
  int b = t * CH, e = b + CH; if (e > NN) e = NN; if (b > NN) b = NN;
  int s = 0;
  for (int i = b; i < e; ++i) s += cnt[i];
  part[t] = s;
  __syncthreads();
  for (int off = 1; off < 1024; off <<= 1) {
    int v = (t >= off) ? part[t - off] : 0;
    __syncthreads();
    part[t] += v;
    __syncthreads();
  }
  int excl = (t == 0) ? 0 : part[t - 1];
  for (int i = b; i < e; ++i) { rowp[i] = excl; excl += cnt[i]; }
  if (t == 1023) rowp[NN] = part[1023];
}

// per edge: write src and f32 edge_attr into CSR (dst-sorted) slots
__global__ __launch_bounds__(256) void k_fill(const int* __restrict__ dst,
                                              const int* __restrict__ src,
                                              const float* __restrict__ eattr,
                                              const int* __restrict__ rowp,
                                              int* __restrict__ cursor,
                                              int* __restrict__ src_csr,
                                              float* __restrict__ attr_csr) {
  for (int e = blockIdx.x * 256 + threadIdx.x; e < NE; e += gridDim.x * 256) {
    int d = dst[e];
    int pos = atomicAdd(&cursor[d], 1);
    int idx = rowp[d] + pos;
    src_csr[idx] = src[e];
    const f32x4* ar = (const f32x4*)(eattr + (long)e * 16);
    f32x4* orow = (f32x4*)&attr_csr[(long)idx * 16];
    f32x4 a0 = ar[0], a1 = ar[1], a2 = ar[2], a3 = ar[3];
    orow[0] = a0; orow[1] = a1; orow[2] = a2; orow[3] = a3;
  }
}

// ---------------- m = h @ convW  (bf16 MFMA, BM=64, all staging via global_load_lds) ----------------
__global__ __launch_bounds__(256) void k_mgemm(const unsigned short* __restrict__ Ab,
                                               const unsigned short* __restrict__ Bp,
                                               unsigned short* __restrict__ O) {
  __shared__ __align__(16) unsigned short As[64 * 128];   // 16KB
  __shared__ __align__(16) unsigned short Bs[128 * 128];  // 32KB
  int tid = threadIdx.x;
  int blockRow = blockIdx.x * 64;
  const unsigned short* asrc = Ab + (long)blockRow * CC;
#pragma unroll
  for (int p = 0; p < 4; ++p) {
    int off8 = (p * 256 + tid) * 8;
    gload16(asrc + off8, As + off8);
  }
#pragma unroll
  for (int p = 0; p < 8; ++p) {
    int off8 = (p * 256 + tid) * 8;
    gload16(Bp + off8, Bs + off8);
  }
  __syncthreads();

  int wave = tid >> 6, lane = tid & 63;
  int rbase = wave * 16;
  int lrow = rbase + (lane & 15);
  int swz = (lane & 7) << 3;
  bf16x8 a[4];
#pragma unroll
  for (int ks = 0; ks < 4; ++ks)
    a[ks] = *(const bf16x8*)&As[lrow * 128 + ((ks * 32 + (lane >> 4) * 8) ^ swz)];

  f32x4 acc[8];
#pragma unroll
  for (int t = 0; t < 8; ++t) acc[t] = {0.f, 0.f, 0.f, 0.f};
#pragma unroll
  for (int t = 0; t < 8; ++t) {
    int col = t * 16 + (lane & 15);
#pragma unroll
    for (int ks = 0; ks < 4; ++ks) {
      bf16x8 bfr = *(const bf16x8*)&Bs[col * 128 + ((ks * 32 + (lane >> 4) * 8) ^ swz)];
      acc[t] = __builtin_amdgcn_mfma_f32_16x16x32_bf16(a[ks], bfr, acc[t], 0, 0, 0);
    }
  }
#pragma unroll
  for (int t = 0; t < 8; ++t) {
    int col = t * 16 + (lane & 15);
#pragma unroll
    for (int q = 0; q < 4; ++q) {
      int grow = blockRow + rbase + (lane >> 4) * 4 + q;
      if (grow < NN) O[(long)grow * CC + col] = f2b(acc[t][q]);
    }
  }
}

// ---------------- aggregate: one wave per node; v_pk_fma_f32 ea projection ----------------
__global__ __launch_bounds__(256) void k_agg(const unsigned short* __restrict__ m,
                                             const float* __restrict__ attr,
                                             const float* __restrict__ eW,
                                             const int* __restrict__ src_csr,
                                             const int* __restrict__ rowp,
                                             unsigned short* __restrict__ agg) {
  int n = blockIdx.x * 4 + (threadIdx.x >> 6);   // NN % 4 == 0
  int t = threadIdx.x & 63;
  f32x2 w[16];
#pragma unroll
  for (int k = 0; k < 16; ++k) w[k] = *(const f32x2*)&eW[k * CC + 2 * t];
  int b = rowp[n], e = rowp[n + 1];
  float acc0 = 0.f, acc1 = 0.f;
#pragma unroll 2
  for (int i = b; i < e; ++i) {
    int s = src_csr[i];
    const f32x4* ap = (const f32x4*)(attr + (long)i * 16);
    F4 A0, A1, A2, A3;
    A0.v = ap[0]; A1.v = ap[1]; A2.v = ap[2]; A3.v = ap[3];
    // two independent 8-deep pk_fma chains (2 fma/instr, op_sel broadcasts a-half)
    f32x2 ea_a = {0.f, 0.f}, ea_b = {0.f, 0.f};
    asm("v_pk_fma_f32 %0, %1, %2, %0 op_sel_hi:[0,1,1]"               : "+v"(ea_a) : "v"(A0.s.lo), "v"(w[0]));
    asm("v_pk_fma_f32 %0, %1, %2, %0 op_sel:[1,0,0] op_sel_hi:[1,1,1]": "+v"(ea_a) : "v"(A0.s.lo), "v"(w[1]));
    asm("v_pk_fma_f32 %0, %1, %2, %0 op_sel_hi:[0,1,1]"               : "+v"(ea_a) : "v"(A0.s.hi), "v"(w[2]));
    asm("v_pk_fma_f32 %0, %1, %2, %0 op_sel:[1,0,0] op_sel_hi:[1,1,1]": "+v"(ea_a) : "v"(A0.s.hi), "v"(w[3]));
    asm("v_pk_fma_f32 %0, %1, %2, %0 op_sel_hi:[0,1,1]"               : "+v"(ea_b) : "v"(A1.s.lo), "v"(w[4]));
    asm("v_pk_fma_f32 %0, %1, %2, %0 op_sel:[1,0,0] op_sel_hi:[1,1,1]": "+v"(ea_b) : "v"(A1.s.lo), "v"(w[5]));
    asm("v_pk_fma_f32 %0, %1, %2, %0 op_sel_hi:[0,1,1]"               : "+v"(ea_b) : "v"(A1.s.hi), "v"(w[6]));
    asm("v_pk_fma_f32 %0, %1, %2, %0 op_sel:[1,0,0] op_sel_hi:[1,1,1]": "+v"(ea_b) : "v"(A1.s.hi), "v"(w[7]));
    asm("v_pk_fma_f32 %0, %1, %2, %0 op_sel_hi:[0,1,1]"               : "+v"(ea_a) : "v"(A2.s.lo), "v"(w[8]));
    asm("v_pk_fma_f32 %0, %1, %2, %0 op_sel:[1,0,0] op_sel_hi:[1,1,1]": "+v"(ea_a) : "v"(A2.s.lo), "v"(w[9]));
    asm("v_pk_fma_f32 %0, %1, %2, %0 op_sel_hi:[0,1,1]"               : "+v"(ea_a) : "v"(A2.s.hi), "v"(w[10]));
    asm("v_pk_fma_f32 %0, %1, %2, %0 op_sel:[1,0,0] op_sel_hi:[1,1,1]": "+v"(ea_a) : "v"(A2.s.hi), "v"(w[11]));
    asm("v_pk_fma_f32 %0, %1, %2, %0 op_sel_hi:[0,1,1]"               : "+v"(ea_b) : "v"(A3.s.lo), "v"(w[12]));
    asm("v_pk_fma_f32 %0, %1, %2, %0 op_sel:[1,0,0] op_sel_hi:[1,1,1]": "+v"(ea_b) : "v"(A3.s.lo), "v"(w[13]));
    asm("v_pk_fma_f32 %0, %1, %2, %0 op_sel_hi:[0,1,1]"               : "+v"(ea_b) : "v"(A3.s.hi), "v"(w[14]));
    asm("v_pk_fma_f32 %0, %1, %2, %0 op_sel:[1,0,0] op_sel_hi:[1,1,1]": "+v"(ea_b) : "v"(A3.s.hi), "v"(w[15]));
    unsigned int mv = *(const unsigned int*)&m[(long)s * CC + 2 * t];
    acc0 += fmaxf(blo(mv) + ea_a.x + ea_b.x, 0.f);
    acc1 += fmaxf(bhi(mv) + ea_a.y + ea_b.y, 0.f);
  }
  float d = (float)(e - b);
  if (d < 1.f) d = 1.f;
  float inv = 1.f / d;
  unsigned int o = (unsigned int)f2b(acc0 * inv) | ((unsigned int)f2b(acc1 * inv) << 16);
  int cidx = (2 * t) ^ ((n & 7) << 3);
  *(unsigned int*)&agg[(long)n * CC + cidx] = o;
}

// ---------------- fused GRU: DMA-staged weights, 3 chunk phases ----------------
__global__ __launch_bounds__(256) void k_gru(const unsigned short* __restrict__ aggb,
                                             const unsigned short* __restrict__ hb,
                                             const float* __restrict__ hin,
                                             const unsigned short* __restrict__ wpack,
                                             const float* __restrict__ bih,
                                             const float* __restrict__ bhh,
                                             float* __restrict__ hout,
                                             unsigned short* __restrict__ houtb,
                                             const float* __restrict__ resid) {
  __shared__ __align__(16) unsigned short Sa[32 * 128];       // 8KB
  __shared__ __align__(16) unsigned short Sh[32 * 128];       // 8KB
  __shared__ __align__(16) unsigned short Ws[2 * 128 * 128];  // 64KB: [wih_c | whh_c]
  int tid = threadIdx.x;
  int blockRow = blockIdx.x * 32;

  const unsigned short* sa_src = aggb + (long)blockRow * CC;
  const unsigned short* sh_src = hb + (long)blockRow * CC;
#pragma unroll
  for (int p = 0; p < 2; ++p) {
    int off8 = (p * 256 + tid) * 8;
    gload16(sa_src + off8, Sa + off8);
    gload16(sh_src + off8, Sh + off8);
  }
#pragma unroll
  for (int p = 0; p < 16; ++p) {
    int off8 = (p * 256 + tid) * 8;
    gload16(wpack + off8, Ws + off8);
  }
  __syncthreads();

  int wave = tid >> 6, lane = tid & 63;
  int r0 = (wave >> 1) * 16;   // 0 or 16
  int cb = (wave & 1) * 64;    // 0 or 64
  int lrow = r0 + (lane & 15);
  int swz = (lane & 7) << 3;
  bf16x8 aA[4], aH[4];
#pragma unroll
  for (int ks = 0; ks < 4; ++ks) {
    int off = lrow * 128 + ((ks * 32 + (lane >> 4) * 8) ^ swz);
    aA[ks] = *(const bf16x8*)&Sa[off];
    aH[ks] = *(const bf16x8*)&Sh[off];
  }

  float rg[4][4], zg[4][4];

#pragma unroll
  for (int chunk = 0; chunk < 3; ++chunk) {
    f32x4 gi[4], gh[4];
#pragma unroll
    for (int t = 0; t < 4; ++t) { gi[t] = {0.f, 0.f, 0.f, 0.f}; gh[t] = {0.f, 0.f, 0.f, 0.f}; }
#pragma unroll
    for (int t = 0; t < 4; ++t) {
      int col = cb + t * 16 + (lane & 15);
#pragma unroll
      for (int ks = 0; ks < 4; ++ks) {
        int wo = col * 128 + ((ks * 32 + (lane >> 4) * 8) ^ swz);
        bf16x8 bi_ = *(const bf16x8*)&Ws[wo];
        gi[t] = __builtin_amdgcn_mfma_f32_16x16x32_bf16(aA[ks], bi_, gi[t], 0, 0, 0);
        bf16x8 bh_ = *(const bf16x8*)&Ws[16384 + wo];
        gh[t] = __builtin_amdgcn_mfma_f32_16x16x32_bf16(aH[ks], bh_, gh[t], 0, 0, 0);
      }
    }
#pragma unroll
    for (int t = 0; t < 4; ++t) {
      int j = cb + t * 16 + (lane & 15);
      int jg = chunk * 128 + j;
      float bi = bih[jg], bh = bhh[jg];
#pragma unroll
      for (int q = 0; q < 4; ++q) {
        float giv = gi[t][q] + bi;
        float ghv = gh[t][q] + bh;
        if (chunk == 0) {
          rg[t][q] = 1.f / (1.f + __expf(-(giv + ghv)));
        } else if (chunk == 1) {
          zg[t][q] = 1.f / (1.f + __expf(-(giv + ghv)));
        } else {
          float nn = tanhf(giv + rg[t][q] * ghv);
          int grow = blockRow + r0 + (lane >> 4) * 4 + q;
          if (grow < NN) {
            long o = (long)grow * CC + j;
            float h = hin[o];
            float z = zg[t][q];
            float hv = (1.f - z) * nn + z * h;
            if (resid) {
              hout[o] = 0.5f * fmaxf(hv, 0.f) + 0.5f * resid[o];
            } else {
              hout[o] = hv;
              houtb[(long)grow * CC + (j ^ ((grow & 7) << 3))] = f2b(hv);
            }
          }
        }
      }
    }
    if (chunk < 2) {
      __syncthreads();  // all waves done reading Ws
      const unsigned short* wsrc = wpack + (long)(chunk + 1) * 32768;
#pragma unroll
      for (int p = 0; p < 16; ++p) {
        int off8 = (p * 256 + tid) * 8;
        gload16(wsrc + off8, Ws + off8);
      }
      __syncthreads();  // staged (compiler drains vmcnt before barrier)
    }
  }
}

extern "C" void kernel_launch(void* const* d_in, const int* in_sizes, int n_in,
                              void* d_out, int out_size, void* d_ws, size_t ws_size,
                              hipStream_t stream) {
  const float* x     = (const float*)d_in[0];
  const int*   eidx  = (const int*)d_in[1];
  const float* eattr = (const float*)d_in[2];
  const float* gamma = (const float*)d_in[3];
  const float* beta  = (const float*)d_in[4];
  const float* eW    = (const float*)d_in[5];
  const float* convW = (const float*)d_in[6];
  const float* wih   = (const float*)d_in[7];
  const float* whh   = (const float*)d_in[8];
  const float* bih   = (const float*)d_in[9];
  const float* bhh   = (const float*)d_in[10];
  float* out = (float*)d_out;

  char* ws = (char*)d_ws;
  size_t off = 0;
  auto alloc = [&](size_t bytes) -> void* {
    void* p = ws + off;
    off += (bytes + 255) & ~(size_t)255;
    return p;
  };
  float* stats   = (float*)alloc(512 * 4);
  int*   cnt     = (int*)alloc((size_t)NN * 4);
  int*   cursor  = (int*)alloc((size_t)NN * 4);
  int*   rowp    = (int*)alloc((size_t)(NN + 1) * 4);
  int*   src_csr = (int*)alloc((size_t)NE * 4);
  float* attr_csr = (float*)alloc((size_t)NE * 16 * 4);
  float* xh      = (float*)alloc((size_t)NN * CC * 4);
  float* h1      = (float*)alloc((size_t)NN * CC * 4);
  unsigned short* xhb  = (unsigned short*)alloc((size_t)NN64 * CC * 2);
  unsigned short* h1b  = (unsigned short*)alloc((size_t)NN64 * CC * 2);
  unsigned short* mb   = (unsigned short*)alloc((size_t)NN64 * CC * 2);
  unsigned short* aggb = (unsigned short*)alloc((size_t)NN64 * CC * 2);
  unsigned short* wpack = (unsigned short*)alloc((size_t)98304 * 2);
  unsigned short* cpack = (unsigned short*)alloc((size_t)32768 * 2);
  (void)ws_size;

  const int* srcv = eidx;
  const int* dstv = eidx + NE;

  hipMemsetAsync(stats, 0, 256 * 4, stream);
  hipMemsetAsync(cnt, 0, (size_t)NN * 4, stream);
  hipMemsetAsync(cursor, 0, (size_t)NN * 4, stream);

  k_prep<<<512, 256, 0, stream>>>(wih, whh, convW, wpack, cpack);
  k_bnstats<<<512, 128, 0, stream>>>(x, stats);
  k_bnfinal<<<1, 128, 0, stream>>>(stats, gamma, beta);
  k_norm<<<2048, 256, 0, stream>>>(x, stats, xh, xhb);

  k_cnt<<<1024, 256, 0, stream>>>(dstv, cnt);
  k_scan<<<1, 1024, 0, stream>>>(cnt, rowp);
  k_fill<<<1024, 256, 0, stream>>>(dstv, srcv, eattr, rowp, cursor, src_csr, attr_csr);

  // layer 0: h0 = xh
  k_mgemm<<<NN64 / 64, 256, 0, stream>>>(xhb, cpack, mb);
  k_agg<<<NN / 4, 256, 0, stream>>>(mb, attr_csr, eW, src_csr, rowp, aggb);
  k_gru<<<(NN + 31) / 32, 256, 0, stream>>>(aggb, xhb, xh, wpack, bih, bhh, h1, h1b, nullptr);

  // layer 1 (+ fused residual epilogue)
  k_mgemm<<<NN64 / 64, 256, 0, stream>>>(h1b, cpack + (size_t)128 * 128, mb);
  k_agg<<<NN / 4, 256, 0, stream>>>(mb, attr_csr, eW, src_csr, rowp, aggb);
  k_gru<<<(NN + 31) / 32, 256, 0, stream>>>(aggb, h1b, h1, wpack, bih, bhh, out, nullptr, xh);
}

// Round 7
// 577.663 us; speedup vs baseline: 1.1777x; 1.1777x over previous
//
#include <hip/hip_runtime.h>

#define NN 50000
#define NN64 50048
#define NE 600000
#define CC 128

typedef float f32x4 __attribute__((ext_vector_type(4)));
typedef float f32x2 __attribute__((ext_vector_type(2)));
typedef short bf16x8 __attribute__((ext_vector_type(8)));
typedef unsigned short u16x4 __attribute__((ext_vector_type(4)));
typedef unsigned short u16x8 __attribute__((ext_vector_type(8)));
typedef _Float16 f16x2 __attribute__((ext_vector_type(2)));
typedef _Float16 f16x4 __attribute__((ext_vector_type(4)));
typedef _Float16 f16x8 __attribute__((ext_vector_type(8)));

#if defined(__has_builtin)
#if __has_builtin(__builtin_amdgcn_fdot2)
#define HAS_FDOT2 1
#endif
#endif

__device__ __forceinline__ unsigned short f2b(float f) {
  union { float f; unsigned int u; } c; c.f = f;
  unsigned int r = c.u + 0x7FFFu + ((c.u >> 16) & 1u);
  return (unsigned short)(r >> 16);
}
// async global->LDS 16B DMA (wave-uniform LDS base + lane*16 semantics; layouts kept linear)
__device__ __forceinline__ void gload16(const unsigned short* g, unsigned short* l) {
  __builtin_amdgcn_global_load_lds((const __attribute__((address_space(1))) void*)g,
                                   (__attribute__((address_space(3))) void*)l, 16, 0, 0);
}

// ---------------- weight prep ----------------
// wpack: [chunk 0..2][ wih_c | whh_c ], each 128x128: [j][k ^ ((j&7)<<3)]  (bf16)
// cpack: [layer 0..1][j][k ^ ((j&7)<<3)]  (bf16; convW[layer] is [k][j])
// ewpk : [kp 0..7][ch 0..127] half2 = (eW[2kp][ch], eW[2kp+1][ch])  (f16)
__global__ __launch_bounds__(256) void k_prep(const float* __restrict__ wih,
                                              const float* __restrict__ whh,
                                              const float* __restrict__ convW,
                                              const float* __restrict__ eW,
                                              unsigned short* __restrict__ wpack,
                                              unsigned short* __restrict__ cpack,
                                              f16x2* __restrict__ ewpk) {
  int i = blockIdx.x * 256 + threadIdx.x;
  if (i < 98304) {
    int k = i & 127, j = (i >> 7) & 127, half = (i >> 14) & 1, chunk = i >> 15;
    const float* srcm = half ? whh : wih;
    float v = srcm[(long)(chunk * 128 + j) * CC + k];
    wpack[(long)(((chunk * 2 + half) * 128 + j) << 7) + (k ^ ((j & 7) << 3))] = f2b(v);
  } else if (i < 131072) {
    int i2 = i - 98304;
    int k = i2 & 127, j = (i2 >> 7) & 127, layer = i2 >> 14;
    float v = convW[(long)(layer * 128 + k) * CC + j];
    cpack[(long)((layer * 128 + j) << 7) + (k ^ ((j & 7) << 3))] = f2b(v);
  } else if (i < 132096) {
    int i2 = i - 131072;
    int kp = i2 >> 7, ch = i2 & 127;
    f16x2 w; w.x = (_Float16)eW[(2 * kp) * CC + ch]; w.y = (_Float16)eW[(2 * kp + 1) * CC + ch];
    ewpk[i2] = w;
  }
}

// ---------------- BatchNorm ----------------
__global__ __launch_bounds__(128) void k_bnstats(const float* __restrict__ x,
                                                 float* __restrict__ stats) {
  int c = threadIdx.x;
  float s = 0.f, s2 = 0.f;
  for (int r = blockIdx.x; r < NN; r += gridDim.x) {
    float v = x[(long)r * CC + c];
    s += v; s2 += v * v;
  }
  atomicAdd(&stats[c], s);
  atomicAdd(&stats[CC + c], s2);
}

__global__ __launch_bounds__(128) void k_bnfinal(float* __restrict__ stats,
                                                 const float* __restrict__ gamma,
                                                 const float* __restrict__ beta) {
  int c = threadIdx.x;
  float mean = stats[c] * (1.f / NN);
  float var = stats[CC + c] * (1.f / NN) - mean * mean;
  var = fmaxf(var, 0.f);
  float sc = gamma[c] * rsqrtf(var + 1e-5f);
  stats[2 * CC + c] = sc;
  stats[3 * CC + c] = beta[c] - mean * sc;
}

// writes xh (f32) + xh_b (bf16, row-swizzled, for MFMA DMA staging)
__global__ __launch_bounds__(256) void k_norm(const float* __restrict__ x,
                                              const float* __restrict__ stats,
                                              float* __restrict__ xh,
                                              unsigned short* __restrict__ xhb) {
  const int total4 = NN * CC / 4;
  for (int i = blockIdx.x * 256 + threadIdx.x; i < total4; i += gridDim.x * 256) {
    f32x4 v = ((const f32x4*)x)[i];
    int c4 = (i & 31) * 4;
    int r = i >> 5;
    f32x4 sc = *(const f32x4*)&stats[2 * CC + c4];
    f32x4 sh = *(const f32x4*)&stats[3 * CC + c4];
    v = v * sc + sh;
    ((f32x4*)xh)[i] = v;
    u16x4 b; b.x = f2b(v[0]); b.y = f2b(v[1]); b.z = f2b(v[2]); b.w = f2b(v[3]);
    *(u16x4*)&xhb[(long)r * CC + (c4 ^ ((r & 7) << 3))] = b;
  }
}

// ---------------- CSR build ----------------
__global__ __launch_bounds__(256) void k_cnt(const int* __restrict__ dst, int* __restrict__ cnt) {
  for (int e = blockIdx.x * 256 + threadIdx.x; e < NE; e += gridDim.x * 256)
    atomicAdd(&cnt[dst[e]], 1);
}

__global__ __launch_bounds__(1024) void k_scan(const int* __restrict__ cnt, int* __restrict__ rowp) {
  __shared__ int part[1024];
  int t = threadIdx.x;
  const int CH = (NN + 1023) / 1024;  // 49
  int b = t * CH, e = b + CH; if (e > NN) e = NN; if (b > NN) b = NN;
  int s = 0;
  for (int i = b; i < e; ++i) s += cnt[i];
  part[t] = s;
  __syncthreads();
  for (int off = 1; off < 1024; off <<= 1) {
    int v = (t >= off) ? part[t - off] : 0;
    __syncthreads();
    part[t] += v;
    __syncthreads();
  }
  int excl = (t == 0) ? 0 : part[t - 1];
  for (int i = b; i < e; ++i) { rowp[i] = excl; excl += cnt[i]; }
  if (t == 1023) rowp[NN] = part[1023];
}

// per edge: write src and f16 edge_attr into CSR (dst-sorted) slots
__global__ __launch_bounds__(256) void k_fill(const int* __restrict__ dst,
                                              const int* __restrict__ src,
                                              const float* __restrict__ eattr,
                                              const int* __restrict__ rowp,
                                              int* __restrict__ cursor,
                                              int* __restrict__ src_csr,
                                              _Float16* __restrict__ attr_csr) {
  for (int e = blockIdx.x * 256 + threadIdx.x; e < NE; e += gridDim.x * 256) {
    int d = dst[e];
    int pos = atomicAdd(&cursor[d], 1);
    int idx = rowp[d] + pos;
    src_csr[idx] = src[e];
    const f32x4* ar = (const f32x4*)(eattr + (long)e * 16);
    f32x4 a0 = ar[0], a1 = ar[1], a2 = ar[2], a3 = ar[3];
    f16x8 h0, h1;
#pragma unroll
    for (int q = 0; q < 4; ++q) { h0[q] = (_Float16)a0[q]; h0[4 + q] = (_Float16)a1[q]; }
#pragma unroll
    for (int q = 0; q < 4; ++q) { h1[q] = (_Float16)a2[q]; h1[4 + q] = (_Float16)a3[q]; }
    f16x8* orow = (f16x8*)&attr_csr[(long)idx * 16];
    orow[0] = h0; orow[1] = h1;
  }
}

// ---------------- m = h @ convW  (bf16 MFMA, BM=64, staging via global_load_lds, f16 out) ----------------
__global__ __launch_bounds__(256) void k_mgemm(const unsigned short* __restrict__ Ab,
                                               const unsigned short* __restrict__ Bp,
                                               _Float16* __restrict__ O) {
  __shared__ __align__(16) unsigned short As[64 * 128];   // 16KB
  __shared__ __align__(16) unsigned short Bs[128 * 128];  // 32KB
  int tid = threadIdx.x;
  int blockRow = blockIdx.x * 64;
  const unsigned short* asrc = Ab + (long)blockRow * CC;
#pragma unroll
  for (int p = 0; p < 4; ++p) {
    int off8 = (p * 256 + tid) * 8;
    gload16(asrc + off8, As + off8);
  }
#pragma unroll
  for (int p = 0; p < 8; ++p) {
    int off8 = (p * 256 + tid) * 8;
    gload16(Bp + off8, Bs + off8);
  }
  __syncthreads();

  int wave = tid >> 6, lane = tid & 63;
  int rbase = wave * 16;
  int lrow = rbase + (lane & 15);
  int swz = (lane & 7) << 3;
  bf16x8 a[4];
#pragma unroll
  for (int ks = 0; ks < 4; ++ks)
    a[ks] = *(const bf16x8*)&As[lrow * 128 + ((ks * 32 + (lane >> 4) * 8) ^ swz)];

  f32x4 acc[8];
#pragma unroll
  for (int t = 0; t < 8; ++t) acc[t] = {0.f, 0.f, 0.f, 0.f};
#pragma unroll
  for (int t = 0; t < 8; ++t) {
    int col = t * 16 + (lane & 15);
#pragma unroll
    for (int ks = 0; ks < 4; ++ks) {
      bf16x8 bfr = *(const bf16x8*)&Bs[col * 128 + ((ks * 32 + (lane >> 4) * 8) ^ swz)];
      acc[t] = __builtin_amdgcn_mfma_f32_16x16x32_bf16(a[ks], bfr, acc[t], 0, 0, 0);
    }
  }
#pragma unroll
  for (int t = 0; t < 8; ++t) {
    int col = t * 16 + (lane & 15);
#pragma unroll
    for (int q = 0; q < 4; ++q) {
      int grow = blockRow + rbase + (lane >> 4) * 4 + q;
      if (grow < NN) O[(long)grow * CC + col] = (_Float16)acc[t][q];
    }
  }
}

// ---------------- aggregate: one wave per node; f16 attr, v_dot2_f32_f16 projection ----------------
__global__ __launch_bounds__(256) void k_agg(const _Float16* __restrict__ m,
                                             const _Float16* __restrict__ attr,
                                             const f16x2* __restrict__ ewpk,
                                             const int* __restrict__ src_csr,
                                             const int* __restrict__ rowp,
                                             unsigned short* __restrict__ agg) {
  int n = blockIdx.x * 4 + (threadIdx.x >> 6);   // NN % 4 == 0
  int t = threadIdx.x & 63;
  f16x2 w0[8], w1[8];
#pragma unroll
  for (int kp = 0; kp < 8; ++kp) {
    f16x4 wv = *(const f16x4*)&ewpk[kp * 128 + 2 * t];  // (ch 2t, ch 2t+1)
    w0[kp].x = wv.x; w0[kp].y = wv.y;
    w1[kp].x = wv.z; w1[kp].y = wv.w;
  }
  int b = rowp[n], e = rowp[n + 1];
  float acc0 = 0.f, acc1 = 0.f;
  union H8 { f16x8 v; f16x2 p[4]; };
#pragma unroll 2
  for (int i = b; i < e; ++i) {
    int s = src_csr[i];
    const f16x8* ap = (const f16x8*)(attr + (long)i * 16);
    H8 A0, A1; A0.v = ap[0]; A1.v = ap[1];
    f16x2 mp = *(const f16x2*)&m[(long)s * CC + 2 * t];
    float s0 = (float)mp.x, s1 = (float)mp.y;   // fold "m +" into dot accumulator
#if HAS_FDOT2
#pragma unroll
    for (int kp = 0; kp < 4; ++kp) {
      s0 = __builtin_amdgcn_fdot2(A0.p[kp], w0[kp], s0, false);
      s1 = __builtin_amdgcn_fdot2(A0.p[kp], w1[kp], s1, false);
    }
#pragma unroll
    for (int kp = 0; kp < 4; ++kp) {
      s0 = __builtin_amdgcn_fdot2(A1.p[kp], w0[4 + kp], s0, false);
      s1 = __builtin_amdgcn_fdot2(A1.p[kp], w1[4 + kp], s1, false);
    }
#else
#pragma unroll
    for (int kp = 0; kp < 4; ++kp) {
      s0 = fmaf((float)A0.p[kp].x, (float)w0[kp].x, s0);
      s0 = fmaf((float)A0.p[kp].y, (float)w0[kp].y, s0);
      s1 = fmaf((float)A0.p[kp].x, (float)w1[kp].x, s1);
      s1 = fmaf((float)A0.p[kp].y, (float)w1[kp].y, s1);
    }
#pragma unroll
    for (int kp = 0; kp < 4; ++kp) {
      s0 = fmaf((float)A1.p[kp].x, (float)w0[4 + kp].x, s0);
      s0 = fmaf((float)A1.p[kp].y, (float)w0[4 + kp].y, s0);
      s1 = fmaf((float)A1.p[kp].x, (float)w1[4 + kp].x, s1);
      s1 = fmaf((float)A1.p[kp].y, (float)w1[4 + kp].y, s1);
    }
#endif
    acc0 += fmaxf(s0, 0.f);
    acc1 += fmaxf(s1, 0.f);
  }
  float d = (float)(e - b);
  if (d < 1.f) d = 1.f;
  float inv = 1.f / d;
  unsigned int o = (unsigned int)f2b(acc0 * inv) | ((unsigned int)f2b(acc1 * inv) << 16);
  int cidx = (2 * t) ^ ((n & 7) << 3);
  *(unsigned int*)&agg[(long)n * CC + cidx] = o;
}

// ---------------- fused GRU: DMA-staged weights, 3 chunk phases ----------------
__global__ __launch_bounds__(256) void k_gru(const unsigned short* __restrict__ aggb,
                                             const unsigned short* __restrict__ hb,
                                             const float* __restrict__ hin,
                                             const unsigned short* __restrict__ wpack,
                                             const float* __restrict__ bih,
                                             const float* __restrict__ bhh,
                                             float* __restrict__ hout,
                                             unsigned short* __restrict__ houtb,
                                             const float* __restrict__ resid) {
  __shared__ __align__(16) unsigned short Sa[32 * 128];       // 8KB
  __shared__ __align__(16) unsigned short Sh[32 * 128];       // 8KB
  __shared__ __align__(16) unsigned short Ws[2 * 128 * 128];  // 64KB: [wih_c | whh_c]
  int tid = threadIdx.x;
  int blockRow = blockIdx.x * 32;

  const unsigned short* sa_src = aggb + (long)blockRow * CC;
  const unsigned short* sh_src = hb + (long)blockRow * CC;
#pragma unroll
  for (int p = 0; p < 2; ++p) {
    int off8 = (p * 256 + tid) * 8;
    gload16(sa_src + off8, Sa + off8);
    gload16(sh_src + off8, Sh + off8);
  }
#pragma unroll
  for (int p = 0; p < 16; ++p) {
    int off8 = (p * 256 + tid) * 8;
    gload16(wpack + off8, Ws + off8);
  }
  __syncthreads();

  int wave = tid >> 6, lane = tid & 63;
  int r0 = (wave >> 1) * 16;   // 0 or 16
  int cb = (wave & 1) * 64;    // 0 or 64
  int lrow = r0 + (lane & 15);
  int swz = (lane & 7) << 3;
  bf16x8 aA[4], aH[4];
#pragma unroll
  for (int ks = 0; ks < 4; ++ks) {
    int off = lrow * 128 + ((ks * 32 + (lane >> 4) * 8) ^ swz);
    aA[ks] = *(const bf16x8*)&Sa[off];
    aH[ks] = *(const bf16x8*)&Sh[off];
  }

  float rg[4][4], zg[4][4];

#pragma unroll
  for (int chunk = 0; chunk < 3; ++chunk) {
    f32x4 gi[4], gh[4];
#pragma unroll
    for (int t = 0; t < 4; ++t) { gi[t] = {0.f, 0.f, 0.f, 0.f}; gh[t] = {0.f, 0.f, 0.f, 0.f}; }
#pragma unroll
    for (int t = 0; t < 4; ++t) {
      int col = cb + t * 16 + (lane & 15);
#pragma unroll
      for (int ks = 0; ks < 4; ++ks) {
        int wo = col * 128 + ((ks * 32 + (lane >> 4) * 8) ^ swz);
        bf16x8 bi_ = *(const bf16x8*)&Ws[wo];
        gi[t] = __builtin_amdgcn_mfma_f32_16x16x32_bf16(aA[ks], bi_, gi[t], 0, 0, 0);
        bf16x8 bh_ = *(const bf16x8*)&Ws[16384 + wo];
        gh[t] = __builtin_amdgcn_mfma_f32_16x16x32_bf16(aH[ks], bh_, gh[t], 0, 0, 0);
      }
    }
#pragma unroll
    for (int t = 0; t < 4; ++t) {
      int j = cb + t * 16 + (lane & 15);
      int jg = chunk * 128 + j;
      float bi = bih[jg], bh = bhh[jg];
#pragma unroll
      for (int q = 0; q < 4; ++q) {
        float giv = gi[t][q] + bi;
        float ghv = gh[t][q] + bh;
        if (chunk == 0) {
          rg[t][q] = 1.f / (1.f + __expf(-(giv + ghv)));
        } else if (chunk == 1) {
          zg[t][q] = 1.f / (1.f + __expf(-(giv + ghv)));
        } else {
          float nn = tanhf(giv + rg[t][q] * ghv);
          int grow = blockRow + r0 + (lane >> 4) * 4 + q;
          if (grow < NN) {
            long o = (long)grow * CC + j;
            float h = hin[o];
            float z = zg[t][q];
            float hv = (1.f - z) * nn + z * h;
            if (resid) {
              hout[o] = 0.5f * fmaxf(hv, 0.f) + 0.5f * resid[o];
            } else {
              hout[o] = hv;
              houtb[(long)grow * CC + (j ^ ((grow & 7) << 3))] = f2b(hv);
            }
          }
        }
      }
    }
    if (chunk < 2) {
      __syncthreads();  // all waves done reading Ws
      const unsigned short* wsrc = wpack + (long)(chunk + 1) * 32768;
#pragma unroll
      for (int p = 0; p < 16; ++p) {
        int off8 = (p * 256 + tid) * 8;
        gload16(wsrc + off8, Ws + off8);
      }
      __syncthreads();  // staged (compiler drains vmcnt before barrier)
    }
  }
}

extern "C" void kernel_launch(void* const* d_in, const int* in_sizes, int n_in,
                              void* d_out, int out_size, void* d_ws, size_t ws_size,
                              hipStream_t stream) {
  const float* x     = (const float*)d_in[0];
  const int*   eidx  = (const int*)d_in[1];
  const float* eattr = (const float*)d_in[2];
  const float* gamma = (const float*)d_in[3];
  const float* beta  = (const float*)d_in[4];
  const float* eW    = (const float*)d_in[5];
  const float* convW = (const float*)d_in[6];
  const float* wih   = (const float*)d_in[7];
  const float* whh   = (const float*)d_in[8];
  const float* bih   = (const float*)d_in[9];
  const float* bhh   = (const float*)d_in[10];
  float* out = (float*)d_out;

  char* ws = (char*)d_ws;
  size_t off = 0;
  auto alloc = [&](size_t bytes) -> void* {
    void* p = ws + off;
    off += (bytes + 255) & ~(size_t)255;
    return p;
  };
  float* stats   = (float*)alloc(512 * 4);
  int*   cnt     = (int*)alloc((size_t)NN * 4);
  int*   cursor  = (int*)alloc((size_t)NN * 4);
  int*   rowp    = (int*)alloc((size_t)(NN + 1) * 4);
  int*   src_csr = (int*)alloc((size_t)NE * 4);
  _Float16* attr_csr = (_Float16*)alloc((size_t)NE * 16 * 2);
  float* xh      = (float*)alloc((size_t)NN * CC * 4);
  float* h1      = (float*)alloc((size_t)NN * CC * 4);
  unsigned short* xhb  = (unsigned short*)alloc((size_t)NN64 * CC * 2);
  unsigned short* h1b  = (unsigned short*)alloc((size_t)NN64 * CC * 2);
  _Float16* mb        = (_Float16*)alloc((size_t)NN64 * CC * 2);
  unsigned short* aggb = (unsigned short*)alloc((size_t)NN64 * CC * 2);
  unsigned short* wpack = (unsigned short*)alloc((size_t)98304 * 2);
  unsigned short* cpack = (unsigned short*)alloc((size_t)32768 * 2);
  f16x2* ewpk    = (f16x2*)alloc((size_t)1024 * 4);
  (void)ws_size;

  const int* srcv = eidx;
  const int* dstv = eidx + NE;

  hipMemsetAsync(stats, 0, 256 * 4, stream);
  hipMemsetAsync(cnt, 0, (size_t)NN * 4, stream);
  hipMemsetAsync(cursor, 0, (size_t)NN * 4, stream);

  k_prep<<<516, 256, 0, stream>>>(wih, whh, convW, eW, wpack, cpack, ewpk);
  k_bnstats<<<512, 128, 0, stream>>>(x, stats);
  k_bnfinal<<<1, 128, 0, stream>>>(stats, gamma, beta);
  k_norm<<<2048, 256, 0, stream>>>(x, stats, xh, xhb);

  k_cnt<<<1024, 256, 0, stream>>>(dstv, cnt);
  k_scan<<<1, 1024, 0, stream>>>(cnt, rowp);
  k_fill<<<1024, 256, 0, stream>>>(dstv, srcv, eattr, rowp, cursor, src_csr, attr_csr);

  // layer 0: h0 = xh
  k_mgemm<<<NN64 / 64, 256, 0, stream>>>(xhb, cpack, mb);
  k_agg<<<NN / 4, 256, 0, stream>>>(mb, attr_csr, ewpk, src_csr, rowp, aggb);
  k_gru<<<(NN + 31) / 32, 256, 0, stream>>>(aggb, xhb, xh, wpack, bih, bhh, h1, h1b, nullptr);

  // layer 1 (+ fused residual epilogue)
  k_mgemm<<<NN64 / 64, 256, 0, stream>>>(h1b, cpack + (size_t)128 * 128, mb);
  k_agg<<<NN / 4, 256, 0, stream>>>(mb, attr_csr, ewpk, src_csr, rowp, aggb);
  k_gru<<<(NN + 31) / 32, 256, 0, stream>>>(aggb, h1b, h1, wpack, bih, bhh, out, nullptr, xh);
}

// Round 8
// 509.576 us; speedup vs baseline: 1.3351x; 1.1336x over previous
//
#include <hip/hip_runtime.h>

#define NN 50000
#define NN64 50048
#define NE 600000
#define CC 128
#define SCANB 196  // ceil(NN/256)

typedef float f32x4 __attribute__((ext_vector_type(4)));
typedef float f32x2 __attribute__((ext_vector_type(2)));
typedef short bf16x8 __attribute__((ext_vector_type(8)));
typedef unsigned short u16x4 __attribute__((ext_vector_type(4)));
typedef unsigned short u16x8 __attribute__((ext_vector_type(8)));
typedef _Float16 f16x2 __attribute__((ext_vector_type(2)));
typedef _Float16 f16x4 __attribute__((ext_vector_type(4)));
typedef _Float16 f16x8 __attribute__((ext_vector_type(8)));

#if defined(__has_builtin)
#if __has_builtin(__builtin_amdgcn_fdot2)
#define HAS_FDOT2 1
#endif
#endif

__device__ __forceinline__ unsigned short f2b(float f) {
  union { float f; unsigned int u; } c; c.f = f;
  unsigned int r = c.u + 0x7FFFu + ((c.u >> 16) & 1u);
  return (unsigned short)(r >> 16);
}
// async global->LDS 16B DMA (wave-uniform LDS base + lane*16 semantics; layouts kept linear)
__device__ __forceinline__ void gload16(const unsigned short* g, unsigned short* l) {
  __builtin_amdgcn_global_load_lds((const __attribute__((address_space(1))) void*)g,
                                   (__attribute__((address_space(3))) void*)l, 16, 0, 0);
}

// ---------------- weight prep ----------------
// wpack: [chunk 0..2][ wih_c | whh_c ], each 128x128: [j][k ^ ((j&7)<<3)]  (bf16)
// cpack: [layer 0..1][j][k ^ ((j&7)<<3)]  (bf16; convW[layer] is [k][j])
// ewpk : [kp 0..7][ch 0..127] half2 = (eW[2kp][ch], eW[2kp+1][ch])  (f16)
__global__ __launch_bounds__(256) void k_prep(const float* __restrict__ wih,
                                              const float* __restrict__ whh,
                                              const float* __restrict__ convW,
                                              const float* __restrict__ eW,
                                              unsigned short* __restrict__ wpack,
                                              unsigned short* __restrict__ cpack,
                                              f16x2* __restrict__ ewpk) {
  int i = blockIdx.x * 256 + threadIdx.x;
  if (i < 98304) {
    int k = i & 127, j = (i >> 7) & 127, half = (i >> 14) & 1, chunk = i >> 15;
    const float* srcm = half ? whh : wih;
    float v = srcm[(long)(chunk * 128 + j) * CC + k];
    wpack[(long)(((chunk * 2 + half) * 128 + j) << 7) + (k ^ ((j & 7) << 3))] = f2b(v);
  } else if (i < 131072) {
    int i2 = i - 98304;
    int k = i2 & 127, j = (i2 >> 7) & 127, layer = i2 >> 14;
    float v = convW[(long)(layer * 128 + k) * CC + j];
    cpack[(long)((layer * 128 + j) << 7) + (k ^ ((j & 7) << 3))] = f2b(v);
  } else if (i < 132096) {
    int i2 = i - 131072;
    int kp = i2 >> 7, ch = i2 & 127;
    f16x2 w; w.x = (_Float16)eW[(2 * kp) * CC + ch]; w.y = (_Float16)eW[(2 * kp + 1) * CC + ch];
    ewpk[i2] = w;
  }
}

// ---------------- BatchNorm ----------------
__global__ __launch_bounds__(128) void k_bnstats(const float* __restrict__ x,
                                                 float* __restrict__ stats) {
  int c = threadIdx.x;
  float s = 0.f, s2 = 0.f;
  for (int r = blockIdx.x; r < NN; r += gridDim.x) {
    float v = x[(long)r * CC + c];
    s += v; s2 += v * v;
  }
  atomicAdd(&stats[c], s);
  atomicAdd(&stats[CC + c], s2);
}

__global__ __launch_bounds__(128) void k_bnfinal(float* __restrict__ stats,
                                                 const float* __restrict__ gamma,
                                                 const float* __restrict__ beta) {
  int c = threadIdx.x;
  float mean = stats[c] * (1.f / NN);
  float var = stats[CC + c] * (1.f / NN) - mean * mean;
  var = fmaxf(var, 0.f);
  float sc = gamma[c] * rsqrtf(var + 1e-5f);
  stats[2 * CC + c] = sc;
  stats[3 * CC + c] = beta[c] - mean * sc;
}

// writes xh (f32) + xh_b (bf16, row-swizzled, for MFMA DMA staging)
__global__ __launch_bounds__(256) void k_norm(const float* __restrict__ x,
                                              const float* __restrict__ stats,
                                              float* __restrict__ xh,
                                              unsigned short* __restrict__ xhb) {
  const int total4 = NN * CC / 4;
  for (int i = blockIdx.x * 256 + threadIdx.x; i < total4; i += gridDim.x * 256) {
    f32x4 v = ((const f32x4*)x)[i];
    int c4 = (i & 31) * 4;
    int r = i >> 5;
    f32x4 sc = *(const f32x4*)&stats[2 * CC + c4];
    f32x4 sh = *(const f32x4*)&stats[3 * CC + c4];
    v = v * sc + sh;
    ((f32x4*)xh)[i] = v;
    u16x4 b; b.x = f2b(v[0]); b.y = f2b(v[1]); b.z = f2b(v[2]); b.w = f2b(v[3]);
    *(u16x4*)&xhb[(long)r * CC + (c4 ^ ((r & 7) << 3))] = b;
  }
}

// ---------------- CSR build ----------------
__global__ __launch_bounds__(256) void k_cnt(const int* __restrict__ dst, int* __restrict__ cnt) {
  for (int e = blockIdx.x * 256 + threadIdx.x; e < NE; e += gridDim.x * 256)
    atomicAdd(&cnt[dst[e]], 1);
}

// 3-phase multi-block exclusive scan of cnt[NN] -> rowp[NN+1]
__global__ __launch_bounds__(256) void k_scan_a(const int* __restrict__ cnt,
                                                int* __restrict__ blocksum) {
  int t = threadIdx.x, b = blockIdx.x;
  int idx = b * 256 + t;
  int v = (idx < NN) ? cnt[idx] : 0;
#pragma unroll
  for (int off = 32; off; off >>= 1) v += __shfl_down(v, off, 64);
  __shared__ int wsum[4];
  if ((t & 63) == 0) wsum[t >> 6] = v;
  __syncthreads();
  if (t == 0) blocksum[b] = wsum[0] + wsum[1] + wsum[2] + wsum[3];
}

__global__ __launch_bounds__(256) void k_scan_b(const int* __restrict__ blocksum,
                                                int* __restrict__ blockoff,
                                                int* __restrict__ rowp) {
  int t = threadIdx.x;
  int v = (t < SCANB) ? blocksum[t] : 0;
  __shared__ int sd[256];
  sd[t] = v;
  __syncthreads();
  for (int off = 1; off < 256; off <<= 1) {
    int x = (t >= off) ? sd[t - off] : 0;
    __syncthreads();
    sd[t] += x;
    __syncthreads();
  }
  blockoff[t] = sd[t] - v;  // exclusive
  if (t == 255) rowp[NN] = sd[255];
}

__global__ __launch_bounds__(256) void k_scan_c(const int* __restrict__ cnt,
                                                const int* __restrict__ blockoff,
                                                int* __restrict__ rowp) {
  int t = threadIdx.x, b = blockIdx.x;
  int idx = b * 256 + t;
  int v = (idx < NN) ? cnt[idx] : 0;
  __shared__ int sd[256];
  sd[t] = v;
  __syncthreads();
  for (int off = 1; off < 256; off <<= 1) {
    int x = (t >= off) ? sd[t - off] : 0;
    __syncthreads();
    sd[t] += x;
    __syncthreads();
  }
  if (idx < NN) rowp[idx] = blockoff[b] + sd[t] - v;
}

// per edge: write src and f16 edge_attr into CSR (dst-sorted) slots
__global__ __launch_bounds__(256) void k_fill(const int* __restrict__ dst,
                                              const int* __restrict__ src,
                                              const float* __restrict__ eattr,
                                              const int* __restrict__ rowp,
                                              int* __restrict__ cursor,
                                              int* __restrict__ src_csr,
                                              _Float16* __restrict__ attr_csr) {
  for (int e = blockIdx.x * 256 + threadIdx.x; e < NE; e += gridDim.x * 256) {
    int d = dst[e];
    int pos = atomicAdd(&cursor[d], 1);
    int idx = rowp[d] + pos;
    src_csr[idx] = src[e];
    const f32x4* ar = (const f32x4*)(eattr + (long)e * 16);
    f32x4 a0 = ar[0], a1 = ar[1], a2 = ar[2], a3 = ar[3];
    f16x8 h0, h1;
#pragma unroll
    for (int q = 0; q < 4; ++q) { h0[q] = (_Float16)a0[q]; h0[4 + q] = (_Float16)a1[q]; }
#pragma unroll
    for (int q = 0; q < 4; ++q) { h1[q] = (_Float16)a2[q]; h1[4 + q] = (_Float16)a3[q]; }
    f16x8* orow = (f16x8*)&attr_csr[(long)idx * 16];
    orow[0] = h0; orow[1] = h1;
  }
}

// ---------------- m = h @ convW  (bf16 MFMA, BM=64, staging via global_load_lds, f16 out) ----------------
__global__ __launch_bounds__(256) void k_mgemm(const unsigned short* __restrict__ Ab,
                                               const unsigned short* __restrict__ Bp,
                                               _Float16* __restrict__ O) {
  __shared__ __align__(16) unsigned short As[64 * 128];   // 16KB
  __shared__ __align__(16) unsigned short Bs[128 * 128];  // 32KB
  int tid = threadIdx.x;
  int blockRow = blockIdx.x * 64;
  const unsigned short* asrc = Ab + (long)blockRow * CC;
#pragma unroll
  for (int p = 0; p < 4; ++p) {
    int off8 = (p * 256 + tid) * 8;
    gload16(asrc + off8, As + off8);
  }
#pragma unroll
  for (int p = 0; p < 8; ++p) {
    int off8 = (p * 256 + tid) * 8;
    gload16(Bp + off8, Bs + off8);
  }
  __syncthreads();

  int wave = tid >> 6, lane = tid & 63;
  int rbase = wave * 16;
  int lrow = rbase + (lane & 15);
  int swz = (lane & 7) << 3;
  bf16x8 a[4];
#pragma unroll
  for (int ks = 0; ks < 4; ++ks)
    a[ks] = *(const bf16x8*)&As[lrow * 128 + ((ks * 32 + (lane >> 4) * 8) ^ swz)];

  f32x4 acc[8];
#pragma unroll
  for (int t = 0; t < 8; ++t) acc[t] = {0.f, 0.f, 0.f, 0.f};
#pragma unroll
  for (int t = 0; t < 8; ++t) {
    int col = t * 16 + (lane & 15);
#pragma unroll
    for (int ks = 0; ks < 4; ++ks) {
      bf16x8 bfr = *(const bf16x8*)&Bs[col * 128 + ((ks * 32 + (lane >> 4) * 8) ^ swz)];
      acc[t] = __builtin_amdgcn_mfma_f32_16x16x32_bf16(a[ks], bfr, acc[t], 0, 0, 0);
    }
  }
#pragma unroll
  for (int t = 0; t < 8; ++t) {
    int col = t * 16 + (lane & 15);
#pragma unroll
    for (int q = 0; q < 4; ++q) {
      int grow = blockRow + rbase + (lane >> 4) * 4 + q;
      if (grow < NN) O[(long)grow * CC + col] = (_Float16)acc[t][q];
    }
  }
}

// ---------------- aggregate: one wave per node; f16 attr, v_dot2_f32_f16 projection ----------------
__global__ __launch_bounds__(256) void k_agg(const _Float16* __restrict__ m,
                                             const _Float16* __restrict__ attr,
                                             const f16x2* __restrict__ ewpk,
                                             const int* __restrict__ src_csr,
                                             const int* __restrict__ rowp,
                                             unsigned short* __restrict__ agg) {
  int n = blockIdx.x * 4 + (threadIdx.x >> 6);   // NN % 4 == 0
  int t = threadIdx.x & 63;
  f16x2 w0[8], w1[8];
#pragma unroll
  for (int kp = 0; kp < 8; ++kp) {
    f16x4 wv = *(const f16x4*)&ewpk[kp * 128 + 2 * t];  // (ch 2t, ch 2t+1)
    w0[kp].x = wv.x; w0[kp].y = wv.y;
    w1[kp].x = wv.z; w1[kp].y = wv.w;
  }
  int b = rowp[n], e = rowp[n + 1];
  float acc0 = 0.f, acc1 = 0.f;
  union H8 { f16x8 v; f16x2 p[4]; };
#pragma unroll 2
  for (int i = b; i < e; ++i) {
    int s = src_csr[i];
    const f16x8* ap = (const f16x8*)(attr + (long)i * 16);
    H8 A0, A1; A0.v = ap[0]; A1.v = ap[1];
    f16x2 mp = *(const f16x2*)&m[(long)s * CC + 2 * t];
    float s0 = (float)mp.x, s1 = (float)mp.y;   // fold "m +" into dot accumulator
#if HAS_FDOT2
#pragma unroll
    for (int kp = 0; kp < 4; ++kp) {
      s0 = __builtin_amdgcn_fdot2(A0.p[kp], w0[kp], s0, false);
      s1 = __builtin_amdgcn_fdot2(A0.p[kp], w1[kp], s1, false);
    }
#pragma unroll
    for (int kp = 0; kp < 4; ++kp) {
      s0 = __builtin_amdgcn_fdot2(A1.p[kp], w0[4 + kp], s0, false);
      s1 = __builtin_amdgcn_fdot2(A1.p[kp], w1[4 + kp], s1, false);
    }
#else
#pragma unroll
    for (int kp = 0; kp < 4; ++kp) {
      s0 = fmaf((float)A0.p[kp].x, (float)w0[kp].x, s0);
      s0 = fmaf((float)A0.p[kp].y, (float)w0[kp].y, s0);
      s1 = fmaf((float)A0.p[kp].x, (float)w1[kp].x, s1);
      s1 = fmaf((float)A0.p[kp].y, (float)w1[kp].y, s1);
    }
#pragma unroll
    for (int kp = 0; kp < 4; ++kp) {
      s0 = fmaf((float)A1.p[kp].x, (float)w0[4 + kp].x, s0);
      s0 = fmaf((float)A1.p[kp].y, (float)w0[4 + kp].y, s0);
      s1 = fmaf((float)A1.p[kp].x, (float)w1[4 + kp].x, s1);
      s1 = fmaf((float)A1.p[kp].y, (float)w1[4 + kp].y, s1);
    }
#endif
    acc0 += fmaxf(s0, 0.f);
    acc1 += fmaxf(s1, 0.f);
  }
  float d = (float)(e - b);
  if (d < 1.f) d = 1.f;
  float inv = 1.f / d;
  unsigned int o = (unsigned int)f2b(acc0 * inv) | ((unsigned int)f2b(acc1 * inv) << 16);
  int cidx = (2 * t) ^ ((n & 7) << 3);
  *(unsigned int*)&agg[(long)n * CC + cidx] = o;
}

// ---------------- fused GRU: DMA-staged weights, 3 chunk phases ----------------
__global__ __launch_bounds__(256) void k_gru(const unsigned short* __restrict__ aggb,
                                             const unsigned short* __restrict__ hb,
                                             const float* __restrict__ hin,
                                             const unsigned short* __restrict__ wpack,
                                             const float* __restrict__ bih,
                                             const float* __restrict__ bhh,
                                             float* __restrict__ hout,
                                             unsigned short* __restrict__ houtb,
                                             const float* __restrict__ resid) {
  __shared__ __align__(16) unsigned short Sa[32 * 128];       // 8KB
  __shared__ __align__(16) unsigned short Sh[32 * 128];       // 8KB
  __shared__ __align__(16) unsigned short Ws[2 * 128 * 128];  // 64KB: [wih_c | whh_c]
  int tid = threadIdx.x;
  int blockRow = blockIdx.x * 32;

  const unsigned short* sa_src = aggb + (long)blockRow * CC;
  const unsigned short* sh_src = hb + (long)blockRow * CC;
#pragma unroll
  for (int p = 0; p < 2; ++p) {
    int off8 = (p * 256 + tid) * 8;
    gload16(sa_src + off8, Sa + off8);
    gload16(sh_src + off8, Sh + off8);
  }
#pragma unroll
  for (int p = 0; p < 16; ++p) {
    int off8 = (p * 256 + tid) * 8;
    gload16(wpack + off8, Ws + off8);
  }
  __syncthreads();

  int wave = tid >> 6, lane = tid & 63;
  int r0 = (wave >> 1) * 16;   // 0 or 16
  int cb = (wave & 1) * 64;    // 0 or 64
  int lrow = r0 + (lane & 15);
  int swz = (lane & 7) << 3;
  bf16x8 aA[4], aH[4];
#pragma unroll
  for (int ks = 0; ks < 4; ++ks) {
    int off = lrow * 128 + ((ks * 32 + (lane >> 4) * 8) ^ swz);
    aA[ks] = *(const bf16x8*)&Sa[off];
    aH[ks] = *(const bf16x8*)&Sh[off];
  }

  float rg[4][4], zg[4][4];

#pragma unroll
  for (int chunk = 0; chunk < 3; ++chunk) {
    f32x4 gi[4], gh[4];
#pragma unroll
    for (int t = 0; t < 4; ++t) { gi[t] = {0.f, 0.f, 0.f, 0.f}; gh[t] = {0.f, 0.f, 0.f, 0.f}; }
#pragma unroll
    for (int t = 0; t < 4; ++t) {
      int col = cb + t * 16 + (lane & 15);
#pragma unroll
      for (int ks = 0; ks < 4; ++ks) {
        int wo = col * 128 + ((ks * 32 + (lane >> 4) * 8) ^ swz);
        bf16x8 bi_ = *(const bf16x8*)&Ws[wo];
        gi[t] = __builtin_amdgcn_mfma_f32_16x16x32_bf16(aA[ks], bi_, gi[t], 0, 0, 0);
        bf16x8 bh_ = *(const bf16x8*)&Ws[16384 + wo];
        gh[t] = __builtin_amdgcn_mfma_f32_16x16x32_bf16(aH[ks], bh_, gh[t], 0, 0, 0);
      }
    }
#pragma unroll
    for (int t = 0; t < 4; ++t) {
      int j = cb + t * 16 + (lane & 15);
      int jg = chunk * 128 + j;
      float bi = bih[jg], bh = bhh[jg];
#pragma unroll
      for (int q = 0; q < 4; ++q) {
        float giv = gi[t][q] + bi;
        float ghv = gh[t][q] + bh;
        if (chunk == 0) {
          rg[t][q] = 1.f / (1.f + __expf(-(giv + ghv)));
        } else if (chunk == 1) {
          zg[t][q] = 1.f / (1.f + __expf(-(giv + ghv)));
        } else {
          float nn = tanhf(giv + rg[t][q] * ghv);
          int grow = blockRow + r0 + (lane >> 4) * 4 + q;
          if (grow < NN) {
            long o = (long)grow * CC + j;
            float h = hin[o];
            float z = zg[t][q];
            float hv = (1.f - z) * nn + z * h;
            if (resid) {
              hout[o] = 0.5f * fmaxf(hv, 0.f) + 0.5f * resid[o];
            } else {
              hout[o] = hv;
              houtb[(long)grow * CC + (j ^ ((grow & 7) << 3))] = f2b(hv);
            }
          }
        }
      }
    }
    if (chunk < 2) {
      __syncthreads();  // all waves done reading Ws
      const unsigned short* wsrc = wpack + (long)(chunk + 1) * 32768;
#pragma unroll
      for (int p = 0; p < 16; ++p) {
        int off8 = (p * 256 + tid) * 8;
        gload16(wsrc + off8, Ws + off8);
      }
      __syncthreads();  // staged (compiler drains vmcnt before barrier)
    }
  }
}

extern "C" void kernel_launch(void* const* d_in, const int* in_sizes, int n_in,
                              void* d_out, int out_size, void* d_ws, size_t ws_size,
                              hipStream_t stream) {
  const float* x     = (const float*)d_in[0];
  const int*   eidx  = (const int*)d_in[1];
  const float* eattr = (const float*)d_in[2];
  const float* gamma = (const float*)d_in[3];
  const float* beta  = (const float*)d_in[4];
  const float* eW    = (const float*)d_in[5];
  const float* convW = (const float*)d_in[6];
  const float* wih   = (const float*)d_in[7];
  const float* whh   = (const float*)d_in[8];
  const float* bih   = (const float*)d_in[9];
  const float* bhh   = (const float*)d_in[10];
  float* out = (float*)d_out;

  char* ws = (char*)d_ws;
  size_t off = 0;
  auto alloc = [&](size_t bytes) -> void* {
    void* p = ws + off;
    off += (bytes + 255) & ~(size_t)255;
    return p;
  };
  float* stats   = (float*)alloc(512 * 4);
  int*   cnt     = (int*)alloc((size_t)NN * 4);
  int*   cursor  = (int*)alloc((size_t)NN * 4);
  int*   rowp    = (int*)alloc((size_t)(NN + 1) * 4);
  int*   blocksum = (int*)alloc(256 * 4);
  int*   blockoff = (int*)alloc(256 * 4);
  int*   src_csr = (int*)alloc((size_t)NE * 4);
  _Float16* attr_csr = (_Float16*)alloc((size_t)NE * 16 * 2);
  float* xh      = (float*)alloc((size_t)NN * CC * 4);
  float* h1      = (float*)alloc((size_t)NN * CC * 4);
  unsigned short* xhb  = (unsigned short*)alloc((size_t)NN64 * CC * 2);
  unsigned short* h1b  = (unsigned short*)alloc((size_t)NN64 * CC * 2);
  _Float16* mb        = (_Float16*)alloc((size_t)NN64 * CC * 2);
  unsigned short* aggb = (unsigned short*)alloc((size_t)NN64 * CC * 2);
  unsigned short* wpack = (unsigned short*)alloc((size_t)98304 * 2);
  unsigned short* cpack = (unsigned short*)alloc((size_t)32768 * 2);
  f16x2* ewpk    = (f16x2*)alloc((size_t)1024 * 4);
  (void)ws_size;

  const int* srcv = eidx;
  const int* dstv = eidx + NE;

  hipMemsetAsync(stats, 0, 256 * 4, stream);
  hipMemsetAsync(cnt, 0, (size_t)NN * 4, stream);
  hipMemsetAsync(cursor, 0, (size_t)NN * 4, stream);

  k_prep<<<516, 256, 0, stream>>>(wih, whh, convW, eW, wpack, cpack, ewpk);
  k_bnstats<<<512, 128, 0, stream>>>(x, stats);
  k_bnfinal<<<1, 128, 0, stream>>>(stats, gamma, beta);
  k_norm<<<2048, 256, 0, stream>>>(x, stats, xh, xhb);

  k_cnt<<<1024, 256, 0, stream>>>(dstv, cnt);
  k_scan_a<<<SCANB, 256, 0, stream>>>(cnt, blocksum);
  k_scan_b<<<1, 256, 0, stream>>>(blocksum, blockoff, rowp);
  k_scan_c<<<SCANB, 256, 0, stream>>>(cnt, blockoff, rowp);
  k_fill<<<1024, 256, 0, stream>>>(dstv, srcv, eattr, rowp, cursor, src_csr, attr_csr);

  // layer 0: h0 = xh
  k_mgemm<<<NN64 / 64, 256, 0, stream>>>(xhb, cpack, mb);
  k_agg<<<NN / 4, 256, 0, stream>>>(mb, attr_csr, ewpk, src_csr, rowp, aggb);
  k_gru<<<(NN + 31) / 32, 256, 0, stream>>>(aggb, xhb, xh, wpack, bih, bhh, h1, h1b, nullptr);

  // layer 1 (+ fused residual epilogue)
  k_mgemm<<<NN64 / 64, 256, 0, stream>>>(h1b, cpack + (size_t)128 * 128, mb);
  k_agg<<<NN / 4, 256, 0, stream>>>(mb, attr_csr, ewpk, src_csr, rowp, aggb);
  k_gru<<<(NN + 31) / 32, 256, 0, stream>>>(aggb, h1b, h1, wpack, bih, bhh, out, nullptr, xh);
}